// Round 6
// baseline (1778.771 us; speedup 1.0000x reference)
//
#include <hip/hip_runtime.h>
#include <hip/hip_cooperative_groups.h>

namespace cg = cooperative_groups;

#define BATCH 32
#define NMAT 1024
#define N_ITERS 20
#define SHIFT 5.0f               // E stores t' = exp(-10*D + 5); e^5 cancels in P=t/S

typedef _Float16 h8 __attribute__((ext_vector_type(8)));

__device__ __forceinline__ float wave_allsum(float s) {
#pragma unroll
    for (int off = 1; off < 64; off <<= 1) s += __shfl_xor(s, off, 64);
    return s;
}

__device__ __forceinline__ float4 f4add(float4 a, float4 b) {
    return make_float4(a.x + b.x, a.y + b.y, a.z + b.z, a.w + b.w);
}

__device__ __forceinline__ void rcp4(const float4 t, float* e) {
    e[0] = __builtin_amdgcn_rcpf(t.x);
    e[1] = __builtin_amdgcn_rcpf(t.y);
    e[2] = __builtin_amdgcn_rcpf(t.z);
    e[3] = __builtin_amdgcn_rcpf(t.w);
}

// cross-wave column-partial reduce through LDS, then coalesced float4 store.
// acc[0..15] are lane's 16 columns (f4 chunks f0, f0+1, f2, f2+1).
__device__ __forceinline__ void publish_cols(float4 (*pc)[256], const float* acc,
                                             int w, int f0, int f2,
                                             float* dstSlab, int tid) {
    __syncthreads();   // pc free from any previous use
    pc[w][f0]     = make_float4(acc[0], acc[1], acc[2], acc[3]);
    pc[w][f0 + 1] = make_float4(acc[4], acc[5], acc[6], acc[7]);
    pc[w][f2]     = make_float4(acc[8], acc[9], acc[10], acc[11]);
    pc[w][f2 + 1] = make_float4(acc[12], acc[13], acc[14], acc[15]);
    __syncthreads();
    float4 o = f4add(f4add(pc[0][tid], pc[1][tid]), f4add(pc[2][tid], pc[3][tid]));
    ((float4*)dstSlab)[tid] = o;
}

// ======================= PATH A: persistent cooperative =======================
// 256 blocks (1/CU guaranteed) x 256 threads. Block j owns 128 rows of batch
// b=j>>3 (8 blocks/batch). Lane L owns cols 8L..8L+7 and 512+8L..512+8L+7.
// E = fp16 exp(-10*D+5) entirely in VGPRs (256/lane).
__global__ __launch_bounds__(256, 1) void sinkhorn_coop(
        const float* __restrict__ D,
        float* __restrict__ P0, float* __restrict__ P1,
        float* __restrict__ Qg, float* __restrict__ out) {
    cg::grid_group grid = cg::this_grid();
    __shared__ float4 pc[4][256];
    float* pf = (float*)pc;

    const int j = blockIdx.x;
    const int b = j >> 3;
    const int w = threadIdx.x >> 6, L = threadIdx.x & 63;
    const int f0 = 2 * L, f2 = 2 * (L + 64);

    h8 Ea[32], Eb[32];
    float acc[16], ev[16];

    if (j == 0 && threadIdx.x == 0) out[0] = 0.f;

    // ---- iteration 0: read D once, build E in regs, ev == 1 ----
#pragma unroll
    for (int q = 0; q < 16; ++q) acc[q] = 0.f;
#pragma unroll
    for (int i = 0; i < 32; ++i) {
        const int r = (j << 7) + (w << 5) + i;
        const float4* Dr = (const float4*)(D + ((size_t)r << 10));
        float4 dv0 = Dr[f0], dv1 = Dr[f0 + 1], dv2 = Dr[f2], dv3 = Dr[f2 + 1];
        float t[16];
        t[0]  = __expf(fmaf(dv0.x, -10.f, SHIFT));
        t[1]  = __expf(fmaf(dv0.y, -10.f, SHIFT));
        t[2]  = __expf(fmaf(dv0.z, -10.f, SHIFT));
        t[3]  = __expf(fmaf(dv0.w, -10.f, SHIFT));
        t[4]  = __expf(fmaf(dv1.x, -10.f, SHIFT));
        t[5]  = __expf(fmaf(dv1.y, -10.f, SHIFT));
        t[6]  = __expf(fmaf(dv1.z, -10.f, SHIFT));
        t[7]  = __expf(fmaf(dv1.w, -10.f, SHIFT));
        t[8]  = __expf(fmaf(dv2.x, -10.f, SHIFT));
        t[9]  = __expf(fmaf(dv2.y, -10.f, SHIFT));
        t[10] = __expf(fmaf(dv2.z, -10.f, SHIFT));
        t[11] = __expf(fmaf(dv2.w, -10.f, SHIFT));
        t[12] = __expf(fmaf(dv3.x, -10.f, SHIFT));
        t[13] = __expf(fmaf(dv3.y, -10.f, SHIFT));
        t[14] = __expf(fmaf(dv3.z, -10.f, SHIFT));
        t[15] = __expf(fmaf(dv3.w, -10.f, SHIFT));
        h8 pa, pb;
#pragma unroll
        for (int q = 0; q < 8; ++q) { pa[q] = (_Float16)t[q]; pb[q] = (_Float16)t[8 + q]; }
        Ea[i] = pa; Eb[i] = pb;
        float s0 = 0.f, s1 = 0.f, s2 = 0.f, s3 = 0.f;
#pragma unroll
        for (int q = 0; q < 4; ++q) {
            s0 += t[q]; s1 += t[4 + q]; s2 += t[8 + q]; s3 += t[12 + q];
        }
        const float s = wave_allsum((s0 + s1) + (s2 + s3));
        const float rs = __builtin_amdgcn_rcpf(s);
#pragma unroll
        for (int q = 0; q < 16; ++q) acc[q] = fmaf(t[q], rs, acc[q]);
    }
    publish_cols(pc, acc, w, f0, f2, P0 + ((size_t)j << 10), threadIdx.x);

    // ---- iterations 1..19 ----
    for (int it = 1; it < N_ITERS; ++it) {
        const bool last = (it == N_ITERS - 1);
        const float* src = (it & 1) ? P0 : P1;
        float* dst = (it & 1) ? P1 : P0;

        grid.sync();

        // ev-reduce: direct global reads of the batch's 8 slabs (my 16 cols)
        {
            float4 s0 = make_float4(0,0,0,0), s1 = s0, s2 = s0, s3 = s0;
#pragma unroll
            for (int k = 0; k < 8; ++k) {
                const float4* Pj = (const float4*)(src + ((size_t)((b << 3) + k) << 10));
                s0 = f4add(s0, Pj[f0]);
                s1 = f4add(s1, Pj[f0 + 1]);
                s2 = f4add(s2, Pj[f2]);
                s3 = f4add(s3, Pj[f2 + 1]);
            }
            rcp4(s0, ev); rcp4(s1, ev + 4); rcp4(s2, ev + 8); rcp4(s3, ev + 12);
        }

        float qacc[16];
#pragma unroll
        for (int q = 0; q < 16; ++q) { acc[q] = 0.f; qacc[q] = 0.f; }
#pragma unroll
        for (int i = 0; i < 32; ++i) {
            float t[16];
#pragma unroll
            for (int q = 0; q < 8; ++q) { t[q] = (float)Ea[i][q]; t[8 + q] = (float)Eb[i][q]; }
            float s0 = 0.f, s1 = 0.f, s2 = 0.f, s3 = 0.f;
#pragma unroll
            for (int q = 0; q < 4; ++q) {
                s0 = fmaf(t[q],      ev[q],      s0);
                s1 = fmaf(t[4 + q],  ev[4 + q],  s1);
                s2 = fmaf(t[8 + q],  ev[8 + q],  s2);
                s3 = fmaf(t[12 + q], ev[12 + q], s3);
            }
            const float s = wave_allsum((s0 + s1) + (s2 + s3));
            const float rs = __builtin_amdgcn_rcpf(s);
#pragma unroll
            for (int q = 0; q < 16; ++q) acc[q] = fmaf(t[q], rs, acc[q]);
            if (last) {
#pragma unroll
                for (int q = 0; q < 16; ++q) {
                    const float d = (SHIFT - __logf(t[q])) * 0.1f;
                    qacc[q] = fmaf(t[q] * d, rs, qacc[q]);
                }
            }
        }
        publish_cols(pc, acc, w, f0, f2, dst + ((size_t)j << 10), threadIdx.x);
        if (last)
            publish_cols(pc, qacc, w, f0, f2, Qg + ((size_t)j << 10), threadIdx.x);
    }

    grid.sync();

    // ---- loss: block j -> batch b, 128 cols; loss = mean_b sum_m ΣQ/ΣP ----
    {
        __syncthreads();
        float c = 0.f;
        if (threadIdx.x < 128) {
            const int col = ((j & 7) << 7) + threadIdx.x;
            float s = 0.f, q = 0.f;
#pragma unroll
            for (int k = 0; k < 8; ++k) {
                const size_t idx = ((size_t)((b << 3) + k) << 10) + col;
                s += P1[idx];
                q += Qg[idx];
            }
            c = q / s;
        }
        c = wave_allsum(c);
        if (L == 0) pf[w] = c;
        __syncthreads();
        if (threadIdx.x == 0)
            atomicAdd(out, (pf[0] + pf[1] + pf[2] + pf[3]) * (1.0f / (float)BATCH));
    }
}

// ======================= PATH B: non-coop fallback =======================
// NPB=16 slabs/batch, 512 blocks, 64 rows/block; ev-reduce folded into each
// pass's prologue (no separate reduce kernel); double-buffered P.

__global__ __launch_bounds__(256) void pass1_fb(const float* __restrict__ D,
                                                _Float16* __restrict__ E,
                                                float* __restrict__ P0) {
    __shared__ float4 pc[4][256];
    const int j = blockIdx.x;
    const int row0 = j << 6;
    const int w = threadIdx.x >> 6, L = threadIdx.x & 63;
    const int f0 = 2 * L, f2 = 2 * (L + 64);

    float acc[16];
#pragma unroll
    for (int q = 0; q < 16; ++q) acc[q] = 0.f;

    for (int i = 0; i < 16; ++i) {
        const int r = row0 + w + (i << 2);
        const float4* Dr = (const float4*)(D + ((size_t)r << 10));
        h8* Er = (h8*)(E + ((size_t)r << 10));
        float4 dv0 = Dr[f0], dv1 = Dr[f0 + 1], dv2 = Dr[f2], dv3 = Dr[f2 + 1];
        float t[16];
        t[0]  = __expf(fmaf(dv0.x, -10.f, SHIFT));
        t[1]  = __expf(fmaf(dv0.y, -10.f, SHIFT));
        t[2]  = __expf(fmaf(dv0.z, -10.f, SHIFT));
        t[3]  = __expf(fmaf(dv0.w, -10.f, SHIFT));
        t[4]  = __expf(fmaf(dv1.x, -10.f, SHIFT));
        t[5]  = __expf(fmaf(dv1.y, -10.f, SHIFT));
        t[6]  = __expf(fmaf(dv1.z, -10.f, SHIFT));
        t[7]  = __expf(fmaf(dv1.w, -10.f, SHIFT));
        t[8]  = __expf(fmaf(dv2.x, -10.f, SHIFT));
        t[9]  = __expf(fmaf(dv2.y, -10.f, SHIFT));
        t[10] = __expf(fmaf(dv2.z, -10.f, SHIFT));
        t[11] = __expf(fmaf(dv2.w, -10.f, SHIFT));
        t[12] = __expf(fmaf(dv3.x, -10.f, SHIFT));
        t[13] = __expf(fmaf(dv3.y, -10.f, SHIFT));
        t[14] = __expf(fmaf(dv3.z, -10.f, SHIFT));
        t[15] = __expf(fmaf(dv3.w, -10.f, SHIFT));
        h8 pa, pb;
#pragma unroll
        for (int q = 0; q < 8; ++q) { pa[q] = (_Float16)t[q]; pb[q] = (_Float16)t[8 + q]; }
        Er[L] = pa; Er[L + 64] = pb;
        float s0 = 0.f, s1 = 0.f, s2 = 0.f, s3 = 0.f;
#pragma unroll
        for (int q = 0; q < 4; ++q) {
            s0 += t[q]; s1 += t[4 + q]; s2 += t[8 + q]; s3 += t[12 + q];
        }
        const float s = wave_allsum((s0 + s1) + (s2 + s3));
        const float rs = __builtin_amdgcn_rcpf(s);
#pragma unroll
        for (int q = 0; q < 16; ++q) acc[q] = fmaf(t[q], rs, acc[q]);
    }
    publish_cols(pc, acc, w, f0, f2, P0 + ((size_t)j << 10), threadIdx.x);
}

template <bool LAST>
__global__ __launch_bounds__(256) void pass_iter_fb(const _Float16* __restrict__ E,
                                                    const float* __restrict__ Psrc,
                                                    float* __restrict__ Pdst,
                                                    float* __restrict__ Qg,
                                                    float* __restrict__ out) {
    __shared__ float4 pc[4][256];
    const int j = blockIdx.x;
    const int row0 = j << 6;
    const int b = j >> 4;
    const int w = threadIdx.x >> 6, L = threadIdx.x & 63;
    const int f0 = 2 * L, f2 = 2 * (L + 64);

    // ev-reduce: 16 slabs split across waves, combine through pc
    float ev[16];
    {
        float4 s0 = make_float4(0,0,0,0), s1 = s0, s2 = s0, s3 = s0;
#pragma unroll
        for (int k = 0; k < 4; ++k) {
            const float4* Pj = (const float4*)(Psrc + ((size_t)((b << 4) + (w << 2) + k) << 10));
            s0 = f4add(s0, Pj[f0]);
            s1 = f4add(s1, Pj[f0 + 1]);
            s2 = f4add(s2, Pj[f2]);
            s3 = f4add(s3, Pj[f2 + 1]);
        }
        pc[w][f0] = s0; pc[w][f0 + 1] = s1; pc[w][f2] = s2; pc[w][f2 + 1] = s3;
        __syncthreads();
        float4 t0 = f4add(f4add(pc[0][f0], pc[1][f0]), f4add(pc[2][f0], pc[3][f0]));
        float4 t1 = f4add(f4add(pc[0][f0+1], pc[1][f0+1]), f4add(pc[2][f0+1], pc[3][f0+1]));
        float4 t2 = f4add(f4add(pc[0][f2], pc[1][f2]), f4add(pc[2][f2], pc[3][f2]));
        float4 t3 = f4add(f4add(pc[0][f2+1], pc[1][f2+1]), f4add(pc[2][f2+1], pc[3][f2+1]));
        rcp4(t0, ev); rcp4(t1, ev + 4); rcp4(t2, ev + 8); rcp4(t3, ev + 12);
    }

    float acc[16], qacc[16];
#pragma unroll
    for (int q = 0; q < 16; ++q) { acc[q] = 0.f; qacc[q] = 0.f; }

    for (int i = 0; i < 16; ++i) {
        const int r = row0 + w + (i << 2);
        const h8* Er = (const h8*)(E + ((size_t)r << 10));
        h8 h0 = Er[L], h1 = Er[L + 64];
        float t[16];
#pragma unroll
        for (int q = 0; q < 8; ++q) { t[q] = (float)h0[q]; t[8 + q] = (float)h1[q]; }
        float s0 = 0.f, s1 = 0.f, s2 = 0.f, s3 = 0.f;
#pragma unroll
        for (int q = 0; q < 4; ++q) {
            s0 = fmaf(t[q],      ev[q],      s0);
            s1 = fmaf(t[4 + q],  ev[4 + q],  s1);
            s2 = fmaf(t[8 + q],  ev[8 + q],  s2);
            s3 = fmaf(t[12 + q], ev[12 + q], s3);
        }
        const float s = wave_allsum((s0 + s1) + (s2 + s3));
        const float rs = __builtin_amdgcn_rcpf(s);
#pragma unroll
        for (int q = 0; q < 16; ++q) acc[q] = fmaf(t[q], rs, acc[q]);
        if (LAST) {
#pragma unroll
            for (int q = 0; q < 16; ++q) {
                const float d = (SHIFT - __logf(t[q])) * 0.1f;
                qacc[q] = fmaf(t[q] * d, rs, qacc[q]);
            }
        }
    }
    publish_cols(pc, acc, w, f0, f2, Pdst + ((size_t)j << 10), threadIdx.x);
    if (LAST) {
        publish_cols(pc, qacc, w, f0, f2, Qg + ((size_t)j << 10), threadIdx.x);
        if (j == 0 && threadIdx.x == 0) out[0] = 0.f;
    }
}

__global__ __launch_bounds__(256) void loss_fb(const float* __restrict__ P,
                                               const float* __restrict__ Qg,
                                               float* __restrict__ out) {
    int g = blockIdx.x * 256 + threadIdx.x;   // 32768
    int b = g >> 10, m = g & 1023;
    const float* Pb = P + (((size_t)b << 4) << 10) + m;
    const float* Qb = Qg + (((size_t)b << 4) << 10) + m;
    float s = 0.f, q = 0.f;
#pragma unroll
    for (int k = 0; k < 16; ++k) {
        s += Pb[(size_t)k << 10];
        q += Qb[(size_t)k << 10];
    }
    float c = q / s;
    c = wave_allsum(c);
    __shared__ float sm[4];
    int w = threadIdx.x >> 6, L = threadIdx.x & 63;
    if (L == 0) sm[w] = c;
    __syncthreads();
    if (threadIdx.x == 0)
        atomicAdd(out, (sm[0] + sm[1] + sm[2] + sm[3]) * (1.0f / (float)BATCH));
}

extern "C" void kernel_launch(void* const* d_in, const int* in_sizes, int n_in,
                              void* d_out, int out_size, void* d_ws, size_t ws_size,
                              hipStream_t stream) {
    const float* D = (const float*)d_in[0];
    float* out = (float*)d_out;

    float* P0 = (float*)d_ws;                          // 512*1024 floats (2 MB)
    float* P1 = P0 + (size_t)512 * 1024;               // 2 MB
    float* Qg = P1 + (size_t)512 * 1024;               // 2 MB
    _Float16* E = (_Float16*)(Qg + (size_t)512 * 1024);// 64 MB (fallback only)

    void* args[] = {(void*)&D, (void*)&P0, (void*)&P1, (void*)&Qg, (void*)&out};
    hipError_t err = hipLaunchCooperativeKernel((const void*)sinkhorn_coop,
                                                dim3(256), dim3(256), args, 0, stream);
    if (err != hipSuccess) {
        (void)hipGetLastError();   // clear sticky error state
        pass1_fb<<<512, 256, 0, stream>>>(D, E, P0);
        for (int t = 1; t < N_ITERS - 1; ++t) {
            const float* src = (t & 1) ? P0 : P1;
            float* dst = (t & 1) ? P1 : P0;
            pass_iter_fb<false><<<512, 256, 0, stream>>>(E, src, dst, Qg, out);
        }
        pass_iter_fb<true><<<512, 256, 0, stream>>>(E, P0, P1, Qg, out);
        loss_fb<<<128, 256, 0, stream>>>(P1, Qg, out);
    }
}

// Round 7
// 777.181 us; speedup vs baseline: 2.2887x; 2.2887x over previous
//
#include <hip/hip_runtime.h>

#define BATCH 32
#define NMAT 1024
#define NBLK 1024            // 32 blocks per batch, 32 rows per block
#define N_ITERS 20
#define SHIFT 6.0f           // t' = exp(-10*D + 6) in [e^-4, e^6] = [0.018, 403] — all
                             // normal e4m3 (max 448). e^SHIFT cancels in t/S.

typedef float vf2 __attribute__((ext_vector_type(2)));

__device__ __forceinline__ float wave_allsum(float s) {
#pragma unroll
    for (int off = 1; off < 64; off <<= 1) s += __shfl_xor(s, off, 64);
    return s;
}

__device__ __forceinline__ float4 f4add(float4 a, float4 b) {
    return make_float4(a.x + b.x, a.y + b.y, a.z + b.z, a.w + b.w);
}

// Zero the three rotating column accumulators + Q accumulator (4 * 32768 floats).
__global__ __launch_bounds__(256) void init_zero(float4* __restrict__ p) {
    p[blockIdx.x * 256 + threadIdx.x] = make_float4(0.f, 0.f, 0.f, 0.f);
}

// Cross-wave combine of per-lane 16-col partials through LDS, then 4 device
// atomics per thread into the batch's column accumulator.
// Lane L owns cols 16L..16L+15 (float4 chunks 4L..4L+3).
__device__ __forceinline__ void publish_atomic(float4 (*pc)[256], const float* acc,
                                               int w, int L, float* dst, int tid) {
    __syncthreads();
    pc[w][4 * L]     = make_float4(acc[0], acc[1], acc[2], acc[3]);
    pc[w][4 * L + 1] = make_float4(acc[4], acc[5], acc[6], acc[7]);
    pc[w][4 * L + 2] = make_float4(acc[8], acc[9], acc[10], acc[11]);
    pc[w][4 * L + 3] = make_float4(acc[12], acc[13], acc[14], acc[15]);
    __syncthreads();
    float4 o = f4add(f4add(pc[0][tid], pc[1][tid]), f4add(pc[2][tid], pc[3][tid]));
    atomicAdd(dst + 4 * tid,     o.x);
    atomicAdd(dst + 4 * tid + 1, o.y);
    atomicAdd(dst + 4 * tid + 2, o.z);
    atomicAdd(dst + 4 * tid + 3, o.w);
}

// Iteration 0: read D (fp32, HBM), build E = fp8 e4m3 of exp(-10D+SHIFT),
// atomic-add first column partials (ev == 1) into W.
__global__ __launch_bounds__(256, 4) void pass1(const float* __restrict__ D,
                                                uint* __restrict__ E,
                                                float* __restrict__ W) {
    __shared__ float4 pc[4][256];
    const int j = blockIdx.x;
    const int b = j >> 5;
    const int w = threadIdx.x >> 6, L = threadIdx.x & 63;

    float acc[16];
#pragma unroll
    for (int q = 0; q < 16; ++q) acc[q] = 0.f;

#pragma unroll
    for (int i = 0; i < 8; ++i) {
        const int r = (j << 5) + w + (i << 2);
        const float4* Dr = (const float4*)(D + ((size_t)r << 10));
        float4 d0 = Dr[4 * L], d1 = Dr[4 * L + 1], d2 = Dr[4 * L + 2], d3 = Dr[4 * L + 3];
        float t[16];
        t[0]  = __expf(fmaf(d0.x, -10.f, SHIFT));
        t[1]  = __expf(fmaf(d0.y, -10.f, SHIFT));
        t[2]  = __expf(fmaf(d0.z, -10.f, SHIFT));
        t[3]  = __expf(fmaf(d0.w, -10.f, SHIFT));
        t[4]  = __expf(fmaf(d1.x, -10.f, SHIFT));
        t[5]  = __expf(fmaf(d1.y, -10.f, SHIFT));
        t[6]  = __expf(fmaf(d1.z, -10.f, SHIFT));
        t[7]  = __expf(fmaf(d1.w, -10.f, SHIFT));
        t[8]  = __expf(fmaf(d2.x, -10.f, SHIFT));
        t[9]  = __expf(fmaf(d2.y, -10.f, SHIFT));
        t[10] = __expf(fmaf(d2.z, -10.f, SHIFT));
        t[11] = __expf(fmaf(d2.w, -10.f, SHIFT));
        t[12] = __expf(fmaf(d3.x, -10.f, SHIFT));
        t[13] = __expf(fmaf(d3.y, -10.f, SHIFT));
        t[14] = __expf(fmaf(d3.z, -10.f, SHIFT));
        t[15] = __expf(fmaf(d3.w, -10.f, SHIFT));
        uint4 o;
        int wd = 0;
        wd = __builtin_amdgcn_cvt_pk_fp8_f32(t[0],  t[1],  wd, false);
        wd = __builtin_amdgcn_cvt_pk_fp8_f32(t[2],  t[3],  wd, true);  o.x = wd;
        wd = 0;
        wd = __builtin_amdgcn_cvt_pk_fp8_f32(t[4],  t[5],  wd, false);
        wd = __builtin_amdgcn_cvt_pk_fp8_f32(t[6],  t[7],  wd, true);  o.y = wd;
        wd = 0;
        wd = __builtin_amdgcn_cvt_pk_fp8_f32(t[8],  t[9],  wd, false);
        wd = __builtin_amdgcn_cvt_pk_fp8_f32(t[10], t[11], wd, true);  o.z = wd;
        wd = 0;
        wd = __builtin_amdgcn_cvt_pk_fp8_f32(t[12], t[13], wd, false);
        wd = __builtin_amdgcn_cvt_pk_fp8_f32(t[14], t[15], wd, true);  o.w = wd;
        ((uint4*)(E + ((size_t)r << 8)))[L] = o;

        float s0 = 0.f, s1 = 0.f, s2 = 0.f, s3 = 0.f;
#pragma unroll
        for (int q = 0; q < 4; ++q) {
            s0 += t[q]; s1 += t[4 + q]; s2 += t[8 + q]; s3 += t[12 + q];
        }
        const float s = wave_allsum((s0 + s1) + (s2 + s3));
        const float rs = __builtin_amdgcn_rcpf(s);
#pragma unroll
        for (int q = 0; q < 16; ++q) acc[q] = fmaf(t[q], rs, acc[q]);
    }
    publish_atomic(pc, acc, w, L, W + (b << 10), threadIdx.x);
}

// Iterations 1..19: read E (fp8), column sums from R -> ev, atomic-add new
// partials into W, zero Z (next-next buffer). LAST also accumulates loss
// partials Q (d reconstructed via log) and arms out[0].
template <bool LAST>
__global__ __launch_bounds__(256, 4) void pass_iter(const uint* __restrict__ E,
                                                    const float* __restrict__ R,
                                                    float* __restrict__ W,
                                                    float* __restrict__ Z,
                                                    float* __restrict__ Qa,
                                                    float* __restrict__ out) {
    __shared__ float4 pc[4][256];
    const int j = blockIdx.x;
    const int b = j >> 5;
    const int w = threadIdx.x >> 6, L = threadIdx.x & 63;

    // zero next-next accumulator (32 blocks cover 32768 floats)
    if (j < 32) ((float4*)Z)[(j << 8) + threadIdx.x] = make_float4(0.f, 0.f, 0.f, 0.f);

    // ev for my 16 columns (R is L2-hot, 4 KB per block, read by all 4 waves)
    float ev[16];
    {
        const float4* Rb = (const float4*)(R + (b << 10));
        float4 r0 = Rb[4 * L], r1 = Rb[4 * L + 1], r2 = Rb[4 * L + 2], r3 = Rb[4 * L + 3];
        ev[0]  = __builtin_amdgcn_rcpf(r0.x);
        ev[1]  = __builtin_amdgcn_rcpf(r0.y);
        ev[2]  = __builtin_amdgcn_rcpf(r0.z);
        ev[3]  = __builtin_amdgcn_rcpf(r0.w);
        ev[4]  = __builtin_amdgcn_rcpf(r1.x);
        ev[5]  = __builtin_amdgcn_rcpf(r1.y);
        ev[6]  = __builtin_amdgcn_rcpf(r1.z);
        ev[7]  = __builtin_amdgcn_rcpf(r1.w);
        ev[8]  = __builtin_amdgcn_rcpf(r2.x);
        ev[9]  = __builtin_amdgcn_rcpf(r2.y);
        ev[10] = __builtin_amdgcn_rcpf(r2.z);
        ev[11] = __builtin_amdgcn_rcpf(r2.w);
        ev[12] = __builtin_amdgcn_rcpf(r3.x);
        ev[13] = __builtin_amdgcn_rcpf(r3.y);
        ev[14] = __builtin_amdgcn_rcpf(r3.z);
        ev[15] = __builtin_amdgcn_rcpf(r3.w);
    }

    float acc[16], qacc[16];
#pragma unroll
    for (int q = 0; q < 16; ++q) { acc[q] = 0.f; qacc[q] = 0.f; }

#pragma unroll
    for (int i = 0; i < 8; ++i) {
        const int r = (j << 5) + w + (i << 2);
        const uint4 h = ((const uint4*)(E + ((size_t)r << 8)))[L];
        float t[16];
        {
            vf2 p;
            p = __builtin_amdgcn_cvt_pk_f32_fp8(h.x, false); t[0]  = p.x; t[1]  = p.y;
            p = __builtin_amdgcn_cvt_pk_f32_fp8(h.x, true);  t[2]  = p.x; t[3]  = p.y;
            p = __builtin_amdgcn_cvt_pk_f32_fp8(h.y, false); t[4]  = p.x; t[5]  = p.y;
            p = __builtin_amdgcn_cvt_pk_f32_fp8(h.y, true);  t[6]  = p.x; t[7]  = p.y;
            p = __builtin_amdgcn_cvt_pk_f32_fp8(h.z, false); t[8]  = p.x; t[9]  = p.y;
            p = __builtin_amdgcn_cvt_pk_f32_fp8(h.z, true);  t[10] = p.x; t[11] = p.y;
            p = __builtin_amdgcn_cvt_pk_f32_fp8(h.w, false); t[12] = p.x; t[13] = p.y;
            p = __builtin_amdgcn_cvt_pk_f32_fp8(h.w, true);  t[14] = p.x; t[15] = p.y;
        }
        float s0 = 0.f, s1 = 0.f, s2 = 0.f, s3 = 0.f;
#pragma unroll
        for (int q = 0; q < 4; ++q) {
            s0 = fmaf(t[q],      ev[q],      s0);
            s1 = fmaf(t[4 + q],  ev[4 + q],  s1);
            s2 = fmaf(t[8 + q],  ev[8 + q],  s2);
            s3 = fmaf(t[12 + q], ev[12 + q], s3);
        }
        const float s = wave_allsum((s0 + s1) + (s2 + s3));
        const float rs = __builtin_amdgcn_rcpf(s);
#pragma unroll
        for (int q = 0; q < 16; ++q) acc[q] = fmaf(t[q], rs, acc[q]);
        if (LAST) {
#pragma unroll
            for (int q = 0; q < 16; ++q) {
                const float d = (SHIFT - __logf(t[q])) * 0.1f;
                qacc[q] = fmaf(t[q] * d, rs, qacc[q]);
            }
        }
    }
    publish_atomic(pc, acc, w, L, W + (b << 10), threadIdx.x);
    if (LAST) {
        publish_atomic(pc, qacc, w, L, Qa + (b << 10), threadIdx.x);
        if (j == 0 && threadIdx.x == 0) out[0] = 0.f;   // arm loss atomics
    }
}

// loss = mean_b sum_m Qa[m] / P[m]   (P = final column sums)
__global__ __launch_bounds__(256) void loss_final(const float* __restrict__ P,
                                                  const float* __restrict__ Qa,
                                                  float* __restrict__ out) {
    const int g = blockIdx.x * 256 + threadIdx.x;   // 32768
    float c = Qa[g] / P[g];
    c = wave_allsum(c);
    __shared__ float sm[4];
    const int w = threadIdx.x >> 6, L = threadIdx.x & 63;
    if (L == 0) sm[w] = c;
    __syncthreads();
    if (threadIdx.x == 0)
        atomicAdd(out, (sm[0] + sm[1] + sm[2] + sm[3]) * (1.0f / (float)BATCH));
}

extern "C" void kernel_launch(void* const* d_in, const int* in_sizes, int n_in,
                              void* d_out, int out_size, void* d_ws, size_t ws_size,
                              hipStream_t stream) {
    const float* D = (const float*)d_in[0];
    float* out = (float*)d_out;

    float* A[3];
    A[0] = (float*)d_ws;                 // 32768 floats each
    A[1] = A[0] + 32768;
    A[2] = A[1] + 32768;
    float* Qa = A[2] + 32768;            // 32768 floats
    uint* E = (uint*)(Qa + 32768);       // 32 MB fp8 (8M uints)

    // zero A[0..2] + Qa (131072 floats = 32768 float4)
    init_zero<<<128, 256, 0, stream>>>((float4*)d_ws);

    // t = 0: build E, partials -> A[1]  (A[2] pre-zeroed by init)
    pass1<<<NBLK, 256, 0, stream>>>(D, E, A[1]);
    // t = 1..18
    for (int t = 1; t < N_ITERS - 1; ++t) {
        pass_iter<false><<<NBLK, 256, 0, stream>>>(E, A[t % 3], A[(t + 1) % 3],
                                                   A[(t + 2) % 3], Qa, out);
    }
    // t = 19: reads A[1], writes A[2] + Qa
    pass_iter<true><<<NBLK, 256, 0, stream>>>(E, A[1], A[2], A[0], Qa, out);
    loss_final<<<128, 256, 0, stream>>>(A[2], Qa, out);
}